// Round 7
// baseline (1555.511 us; speedup 1.0000x reference)
//
#include <hip/hip_runtime.h>

// K-means assignment, two-phase:
//   Phase 1 (screen): hh-only MFMA GEMM (1 fp16 plane) + per-row top-2.
//     gap > MARGIN  -> hh-argmin == exact argmin (write it)
//     gap <= MARGIN -> flag row (-1) for rescue.
//   Phase 2 (rescue): per-512-row-segment compaction, then the VERBATIM
//     round-6 3-term split-fp16 chain (hh+hl+lh, same order, same epilogue,
//     same x2/c2 bits) on gathered 128-row tiles -> bit-identical to round-6
//     (which passed absmax 0). Knife-edge/tie rows always get rescued.
// Round-6 post-mortem: LDS pipe = 43% busy (binding), MFMA 8%; screen halves
// LDS instrs AND cuts MFMA work 3x on ~90% of rows.

#define N_PTS 131072
#define K_CL  2048
#define D_DIM 512
#define BM 128
#define BN 128
#define BK 32
#define LDK 40   // padded LDS row stride in f16 (80 B)
#define NIT ((K_CL / BN) * (D_DIM / BK))   // 256
#define MARGIN 0.25f   // ~13 sigma of the dropped hl+lh correction (rms ~0.019)

typedef _Float16 half8  __attribute__((ext_vector_type(8)));
typedef _Float16 half4v __attribute__((ext_vector_type(4)));
typedef float    floatx4 __attribute__((ext_vector_type(4)));

// ---- c2 norms: one wave per row (VERBATIM round-2/6; bit-proven) ----
__global__ void row_norms_kernel(const float* __restrict__ A,
                                 float* __restrict__ out, int rows) {
    int gid  = blockIdx.x * blockDim.x + threadIdx.x;
    int wave = gid >> 6;
    int lane = gid & 63;
    if (wave >= rows) return;
    const float4* a = (const float4*)(A + (size_t)wave * D_DIM);
    float4 p = a[lane];
    float4 q = a[lane + 64];
    float s = p.x*p.x + p.y*p.y + p.z*p.z + p.w*p.w
            + q.x*q.x + q.y*q.y + q.z*q.z + q.w*q.w;
    #pragma unroll
    for (int off = 32; off > 0; off >>= 1) s += __shfl_down(s, off, 64);
    if (lane == 0) out[wave] = s;
}

// ---- fp32 -> (hi,lo) fp16 planes; one wave per row (VERBATIM round-6) ----
__global__ void conv_f16x2_kernel(const float* __restrict__ src,
                                  _Float16* __restrict__ hi,
                                  _Float16* __restrict__ lo, int rows) {
    int gid = blockIdx.x * blockDim.x + threadIdx.x;
    int row = gid >> 6, lane = gid & 63;
    if (row >= rows) return;
    const float4* a = (const float4*)(src + (size_t)row * D_DIM);
    float4 p = a[lane];
    float4 q = a[lane + 64];
    half4v ph, pl, qh, ql;
    ph.x=(_Float16)p.x; ph.y=(_Float16)p.y; ph.z=(_Float16)p.z; ph.w=(_Float16)p.w;
    qh.x=(_Float16)q.x; qh.y=(_Float16)q.y; qh.z=(_Float16)q.z; qh.w=(_Float16)q.w;
    pl.x=(_Float16)(p.x-(float)ph.x); pl.y=(_Float16)(p.y-(float)ph.y);
    pl.z=(_Float16)(p.z-(float)ph.z); pl.w=(_Float16)(p.w-(float)ph.w);
    ql.x=(_Float16)(q.x-(float)qh.x); ql.y=(_Float16)(q.y-(float)qh.y);
    ql.z=(_Float16)(q.z-(float)qh.z); ql.w=(_Float16)(q.w-(float)qh.w);
    *(half4v*)(hi + (size_t)row * D_DIM +       lane * 4) = ph;
    *(half4v*)(hi + (size_t)row * D_DIM + 256 + lane * 4) = qh;
    *(half4v*)(lo + (size_t)row * D_DIM +       lane * 4) = pl;
    *(half4v*)(lo + (size_t)row * D_DIM + 256 + lane * 4) = ql;
}

// fp32x8 (two float4) -> hi/lo half8 (same rounding ops as conv kernel)
#define SPLIT8(h_, l_, v0_, v1_) do {                                   \
    h_[0]=(_Float16)v0_.x; h_[1]=(_Float16)v0_.y;                       \
    h_[2]=(_Float16)v0_.z; h_[3]=(_Float16)v0_.w;                       \
    h_[4]=(_Float16)v1_.x; h_[5]=(_Float16)v1_.y;                       \
    h_[6]=(_Float16)v1_.z; h_[7]=(_Float16)v1_.w;                       \
    l_[0]=(_Float16)(v0_.x-(float)h_[0]); l_[1]=(_Float16)(v0_.y-(float)h_[1]); \
    l_[2]=(_Float16)(v0_.z-(float)h_[2]); l_[3]=(_Float16)(v0_.w-(float)h_[3]); \
    l_[4]=(_Float16)(v1_.x-(float)h_[4]); l_[5]=(_Float16)(v1_.y-(float)h_[5]); \
    l_[6]=(_Float16)(v1_.z-(float)h_[6]); l_[7]=(_Float16)(v1_.w-(float)h_[7]); \
} while (0)

// ====================== Phase 1: hh-only screen ======================
__global__ __launch_bounds__(256, 3)
void kmeans_screen(const float* __restrict__ X, const float* __restrict__ C,
                   const _Float16* __restrict__ Xhi,
                   const float* __restrict__ c2g, int* __restrict__ out) {
    __shared__ __align__(16) _Float16 sXh[BM * LDK];
    __shared__ __align__(16) _Float16 sCh[BN * LDK];
    __shared__ float c2s[K_CL];
    __shared__ float x2s[BM];    // ~29 KB LDS total

    const int tid  = threadIdx.x;
    const int lane = tid & 63;
    const int w    = tid >> 6;
    const int wti  = w >> 1;
    const int wtj  = w & 1;
    const int q    = lane >> 4;
    const int m16  = lane & 15;
    const int rowBase = blockIdx.x * BM;

    #pragma unroll
    for (int i = tid; i < K_CL / 4; i += 256)
        ((float4*)c2s)[i] = ((const float4*)c2g)[i];

    // x2 into LDS (VERBATIM round-6 in-block code)
    {
        int r = tid & 127, h = tid >> 7;
        const float4* xp = (const float4*)(X + (size_t)(rowBase + r) * D_DIM + h * 256);
        float s0 = 0.f, s1 = 0.f;
        for (int j = 0; j < 64; j += 2) {
            float4 a = xp[j], b = xp[j + 1];
            s0 += a.x*a.x + a.y*a.y + a.z*a.z + a.w*a.w;
            s1 += b.x*b.x + b.y*b.y + b.z*b.z + b.w*b.w;
        }
        ((float*)sXh)[tid] = s0 + s1;
    }
    __syncthreads();
    if (tid < BM) x2s[tid] = ((float*)sXh)[tid] + ((float*)sXh)[tid + 128];

    float bestV[4][4], best2[4][4];
    int   bestI[4][4];
    #pragma unroll
    for (int ti = 0; ti < 4; ++ti)
        #pragma unroll
        for (int r = 0; r < 4; ++r) {
            bestV[ti][r] = 3.4e38f; best2[ti][r] = 3.4e38f; bestI[ti][r] = 0;
        }

    // staging: thread -> row p_row (0..127), 16-f16 half p_h
    const int p_row = tid >> 1;
    const int p_h   = tid & 1;

    float4 rxa, rxb, rc0, rc1, rc2, rc3;   // named regs (no arrays: r5 spill lesson)

#define P1_PREFETCH(nit) do {                                              \
    const int nkt_ = (nit) >> 4, ndt_ = (nit) & 15;                        \
    const int d0_  = ndt_ * BK + p_h * 16;                                 \
    size_t xr_ = (size_t)(rowBase + p_row) * D_DIM + d0_;                  \
    rxa = *(const float4*)(Xhi + xr_);                                     \
    rxb = *(const float4*)(Xhi + xr_ + 8);                                 \
    const float* cp_ = C + (size_t)(nkt_ * BN + p_row) * D_DIM + d0_;      \
    rc0 = *(const float4*)(cp_);      rc1 = *(const float4*)(cp_ + 4);     \
    rc2 = *(const float4*)(cp_ + 8);  rc3 = *(const float4*)(cp_ + 12);    \
} while (0)

    floatx4 acc[4][4];
    #pragma unroll
    for (int ti = 0; ti < 4; ++ti)
        #pragma unroll
        for (int tj = 0; tj < 4; ++tj) acc[ti][tj] = (floatx4){0.f, 0.f, 0.f, 0.f};

    P1_PREFETCH(0);

    #pragma unroll 1
    for (int it = 0; it < NIT; ++it) {
        __syncthreads();
        {   // regs -> LDS (X hi plane direct; C hi from fp32, conv-kernel bits)
            *(float4*)&sXh[p_row * LDK + p_h * 16]     = rxa;
            *(float4*)&sXh[p_row * LDK + p_h * 16 + 8] = rxb;
            half8 h0, h1;
            h0[0]=(_Float16)rc0.x; h0[1]=(_Float16)rc0.y;
            h0[2]=(_Float16)rc0.z; h0[3]=(_Float16)rc0.w;
            h0[4]=(_Float16)rc1.x; h0[5]=(_Float16)rc1.y;
            h0[6]=(_Float16)rc1.z; h0[7]=(_Float16)rc1.w;
            h1[0]=(_Float16)rc2.x; h1[1]=(_Float16)rc2.y;
            h1[2]=(_Float16)rc2.z; h1[3]=(_Float16)rc2.w;
            h1[4]=(_Float16)rc3.x; h1[5]=(_Float16)rc3.y;
            h1[6]=(_Float16)rc3.z; h1[7]=(_Float16)rc3.w;
            *(half8*)&sCh[p_row * LDK + p_h * 16]     = h0;
            *(half8*)&sCh[p_row * LDK + p_h * 16 + 8] = h1;
        }
        __syncthreads();
        if (it + 1 < NIT) P1_PREFETCH(it + 1);

        half8 ah[4];
        #pragma unroll
        for (int ti = 0; ti < 4; ++ti)
            ah[ti] = *(const half8*)&sXh[(wti * 64 + ti * 16 + m16) * LDK + q * 8];
        #pragma unroll
        for (int tj = 0; tj < 4; ++tj) {
            half8 bh = *(const half8*)&sCh[(wtj * 64 + tj * 16 + m16) * LDK + q * 8];
            #pragma unroll
            for (int ti = 0; ti < 4; ++ti)
                acc[ti][tj] = __builtin_amdgcn_mfma_f32_16x16x32_f16(
                                  ah[ti], bh, acc[ti][tj], 0, 0, 0);
        }

        if ((it & 15) == 15) {   // top-2 epilogue per col tile
            const int k0 = (it >> 4) * BN;
            #pragma unroll
            for (int tj = 0; tj < 4; ++tj) {
                int col = k0 + wtj * 64 + tj * 16 + m16;
                float cv = c2s[col];
                #pragma unroll
                for (int ti = 0; ti < 4; ++ti)
                    #pragma unroll
                    for (int r = 0; r < 4; ++r) {
                        float s = x2s[wti * 64 + ti * 16 + q * 4 + r] + cv;
                        float v = s - 2.0f * acc[ti][tj][r];
                        if (v < bestV[ti][r]) {
                            best2[ti][r] = bestV[ti][r];
                            bestV[ti][r] = v; bestI[ti][r] = col;
                        } else if (v < best2[ti][r]) {
                            best2[ti][r] = v;
                        }
                        acc[ti][tj][r] = 0.0f;
                    }
            }
        }
    }

    // cross-lane top-2 merge over the 16 lanes sharing each row
    #pragma unroll
    for (int ti = 0; ti < 4; ++ti)
        #pragma unroll
        for (int r = 0; r < 4; ++r) {
            float v1 = bestV[ti][r], v2 = best2[ti][r];
            int   i1 = bestI[ti][r];
            #pragma unroll
            for (int off = 1; off < 16; off <<= 1) {
                float ov1 = __shfl_xor(v1, off, 64);
                int   oi1 = __shfl_xor(i1, off, 64);
                float ov2 = __shfl_xor(v2, off, 64);
                if (ov1 < v1 || (ov1 == v1 && oi1 < i1)) {
                    v2 = fminf(v1, ov2); v1 = ov1; i1 = oi1;
                } else {
                    v2 = fminf(v2, ov1);
                }
            }
            bestV[ti][r] = v1; best2[ti][r] = v2; bestI[ti][r] = i1;
        }

    __syncthreads();
    float* rv1 = (float*)sXh;        // [128][2]
    int*   ri1 = (int*)sCh;          // [128][2]
    float* rv2 = c2s;                // [128][2] (c2s dead now)
    if (m16 == 0) {
        #pragma unroll
        for (int ti = 0; ti < 4; ++ti)
            #pragma unroll
            for (int r = 0; r < 4; ++r) {
                int rloc = wti * 64 + ti * 16 + q * 4 + r;
                rv1[rloc * 2 + wtj] = bestV[ti][r];
                ri1[rloc * 2 + wtj] = bestI[ti][r];
                rv2[rloc * 2 + wtj] = best2[ti][r];
            }
    }
    __syncthreads();
    if (tid < BM) {
        float av1 = rv1[tid*2], av2 = rv2[tid*2]; int ai1 = ri1[tid*2];
        float bv1 = rv1[tid*2+1], bv2 = rv2[tid*2+1]; int bi1 = ri1[tid*2+1];
        float v1, v2; int i1;
        if (bv1 < av1 || (bv1 == av1 && bi1 < ai1)) {
            v1 = bv1; i1 = bi1; v2 = fminf(av1, bv2);
        } else {
            v1 = av1; i1 = ai1; v2 = fminf(av2, bv1);
        }
        out[rowBase + tid] = (v2 - v1 > MARGIN) ? i1 : -1;
    }
}

// ====================== Phase 2: bit-exact rescue ======================
// Block owns 512 rows; compacts flagged rows; runs the VERBATIM round-6
// 3-term chain on gathered 128-row tiles (X from pre-converted planes,
// C split on the fly with conv-kernel-identical rounding).
__global__ __launch_bounds__(256, 3)
void kmeans_rescue(const float* __restrict__ X, const float* __restrict__ C,
                   const _Float16* __restrict__ Xhi, const _Float16* __restrict__ Xlo,
                   const float* __restrict__ c2g, int* __restrict__ out) {
    __shared__ __align__(16) _Float16 sXh[BM * LDK], sXl[BM * LDK];
    __shared__ __align__(16) _Float16 sCh[BN * LDK], sCl[BN * LDK];
    __shared__ float c2s[K_CL];
    __shared__ float x2s[BM];
    __shared__ int rlist[512];
    __shared__ int rid[BM];
    __shared__ int s_cnt;

    const int tid  = threadIdx.x;
    const int lane = tid & 63;
    const int w    = tid >> 6;
    const int wti  = w >> 1;
    const int wtj  = w & 1;
    const int q    = lane >> 4;
    const int m16  = lane & 15;
    const int seg  = blockIdx.x * 512;

    if (tid == 0) s_cnt = 0;
    __syncthreads();
    for (int i = tid; i < 512; i += 256)
        if (out[seg + i] < 0) { int p = atomicAdd(&s_cnt, 1); rlist[p] = seg + i; }
    __syncthreads();
    const int nt = s_cnt;
    if (nt == 0) return;

    #pragma unroll
    for (int i = tid; i < K_CL / 4; i += 256)
        ((float4*)c2s)[i] = ((const float4*)c2g)[i];

    const int s_row = tid >> 2;
    const int s_f4  = tid & 3;
    const int npass = (nt + BM - 1) >> 7;

    #pragma unroll 1
    for (int p = 0; p < npass; ++p) {
        __syncthreads();     // previous pass's scratch reads done
        if (tid < BM) {
            int idx = p * BM + tid;
            rid[tid] = rlist[idx < nt ? idx : nt - 1];
        }
        __syncthreads();

        // x2 (VERBATIM round-6 math, row indirected)
        {
            int r = tid & 127, h = tid >> 7;
            const float4* xp =
                (const float4*)(X + (size_t)rid[r] * D_DIM + h * 256);
            float s0 = 0.f, s1 = 0.f;
            for (int j = 0; j < 64; j += 2) {
                float4 a = xp[j], b = xp[j + 1];
                s0 += a.x*a.x + a.y*a.y + a.z*a.z + a.w*a.w;
                s1 += b.x*b.x + b.y*b.y + b.z*b.z + b.w*b.w;
            }
            ((float*)sXh)[tid] = s0 + s1;
        }
        __syncthreads();
        if (tid < BM) x2s[tid] = ((float*)sXh)[tid] + ((float*)sXh)[tid + 128];

        const int rs0 = rid[s_row], rs1 = rid[s_row + 64];

        float bestV[4][4];
        int   bestI[4][4];
        #pragma unroll
        for (int ti = 0; ti < 4; ++ti)
            #pragma unroll
            for (int r = 0; r < 4; ++r) { bestV[ti][r] = 3.4e38f; bestI[ti][r] = 0; }

        float4 rXh0, rXh1, rXl0, rXl1, rCa0, rCb0, rCa1, rCb1;

#define P2_PREFETCH(nit) do {                                              \
    const int nkt_ = (nit) >> 4, ndt_ = (nit) & 15;                        \
    const int d0_  = ndt_ * BK + s_f4 * 8;                                 \
    size_t xr0_ = (size_t)rs0 * D_DIM + d0_;                               \
    size_t xr1_ = (size_t)rs1 * D_DIM + d0_;                               \
    size_t cr0_ = (size_t)(nkt_ * BN + s_row) * D_DIM + d0_;               \
    size_t cr1_ = cr0_ + (size_t)64 * D_DIM;                               \
    rXh0 = *(const float4*)(Xhi + xr0_);                                   \
    rXh1 = *(const float4*)(Xhi + xr1_);                                   \
    rXl0 = *(const float4*)(Xlo + xr0_);                                   \
    rXl1 = *(const float4*)(Xlo + xr1_);                                   \
    rCa0 = *(const float4*)(C + cr0_);  rCb0 = *(const float4*)(C + cr0_ + 4); \
    rCa1 = *(const float4*)(C + cr1_);  rCb1 = *(const float4*)(C + cr1_ + 4); \
} while (0)

        floatx4 acc[4][4];
        #pragma unroll
        for (int ti = 0; ti < 4; ++ti)
            #pragma unroll
            for (int tj = 0; tj < 4; ++tj) acc[ti][tj] = (floatx4){0.f,0.f,0.f,0.f};

        P2_PREFETCH(0);

        #pragma unroll 1
        for (int it = 0; it < NIT; ++it) {
            __syncthreads();
            {
                const int r0 = s_row, r1 = s_row + 64;
                *(float4*)&sXh[r0 * LDK + s_f4 * 8] = rXh0;
                *(float4*)&sXh[r1 * LDK + s_f4 * 8] = rXh1;
                *(float4*)&sXl[r0 * LDK + s_f4 * 8] = rXl0;
                *(float4*)&sXl[r1 * LDK + s_f4 * 8] = rXl1;
                half8 h, l;
                SPLIT8(h, l, rCa0, rCb0);
                *(half8*)&sCh[r0 * LDK + s_f4 * 8] = h;
                *(half8*)&sCl[r0 * LDK + s_f4 * 8] = l;
                SPLIT8(h, l, rCa1, rCb1);
                *(half8*)&sCh[r1 * LDK + s_f4 * 8] = h;
                *(half8*)&sCl[r1 * LDK + s_f4 * 8] = l;
            }
            __syncthreads();
            if (it + 1 < NIT) P2_PREFETCH(it + 1);

            // VERBATIM round-6 MFMA chain (hh, hl, lh per dt)
            half8 ah[4], al[4];
            #pragma unroll
            for (int ti = 0; ti < 4; ++ti) {
                int row = wti * 64 + ti * 16 + m16;
                ah[ti] = *(const half8*)&sXh[row * LDK + q * 8];
                al[ti] = *(const half8*)&sXl[row * LDK + q * 8];
            }
            #pragma unroll
            for (int tj = 0; tj < 4; ++tj) {
                int col = wtj * 64 + tj * 16 + m16;
                half8 bh = *(const half8*)&sCh[col * LDK + q * 8];
                half8 bl = *(const half8*)&sCl[col * LDK + q * 8];
                #pragma unroll
                for (int ti = 0; ti < 4; ++ti) {
                    floatx4 a = acc[ti][tj];
                    a = __builtin_amdgcn_mfma_f32_16x16x32_f16(ah[ti], bh, a, 0, 0, 0);
                    a = __builtin_amdgcn_mfma_f32_16x16x32_f16(ah[ti], bl, a, 0, 0, 0);
                    a = __builtin_amdgcn_mfma_f32_16x16x32_f16(al[ti], bh, a, 0, 0, 0);
                    acc[ti][tj] = a;
                }
            }

            if ((it & 15) == 15) {   // VERBATIM round-6 epilogue
                const int k0 = (it >> 4) * BN;
                #pragma unroll
                for (int tj = 0; tj < 4; ++tj) {
                    int col = k0 + wtj * 64 + tj * 16 + m16;
                    float cv = c2s[col];
                    #pragma unroll
                    for (int ti = 0; ti < 4; ++ti)
                        #pragma unroll
                        for (int r = 0; r < 4; ++r) {
                            float s = x2s[wti * 64 + ti * 16 + q * 4 + r] + cv;
                            float v = s - 2.0f * acc[ti][tj][r];
                            if (v < bestV[ti][r]) { bestV[ti][r] = v; bestI[ti][r] = col; }
                            acc[ti][tj][r] = 0.0f;
                        }
                }
            }
        }

        // VERBATIM round-6 reduce; write via rid
        #pragma unroll
        for (int ti = 0; ti < 4; ++ti)
            #pragma unroll
            for (int r = 0; r < 4; ++r) {
                float v = bestV[ti][r]; int ix = bestI[ti][r];
                #pragma unroll
                for (int off = 1; off < 16; off <<= 1) {
                    float ov = __shfl_xor(v, off, 64);
                    int   oi = __shfl_xor(ix, off, 64);
                    if (ov < v || (ov == v && oi < ix)) { v = ov; ix = oi; }
                }
                bestV[ti][r] = v; bestI[ti][r] = ix;
            }

        __syncthreads();
        float* rv  = (float*)sXh;
        int*   rix = (int*)sCh;
        if (m16 == 0) {
            #pragma unroll
            for (int ti = 0; ti < 4; ++ti)
                #pragma unroll
                for (int r = 0; r < 4; ++r) {
                    int rloc = wti * 64 + ti * 16 + q * 4 + r;
                    rv[rloc * 2 + wtj]  = bestV[ti][r];
                    rix[rloc * 2 + wtj] = bestI[ti][r];
                }
        }
        __syncthreads();
        if (tid < BM) {
            float v0 = rv[tid * 2], v1 = rv[tid * 2 + 1];
            int   i0 = rix[tid * 2], i1 = rix[tid * 2 + 1];
            out[rid[tid]] = (v1 < v0 || (v1 == v0 && i1 < i0)) ? i1 : i0;
        }
    }
}

extern "C" void kernel_launch(void* const* d_in, const int* in_sizes, int n_in,
                              void* d_out, int out_size, void* d_ws, size_t ws_size,
                              hipStream_t stream) {
    const float* X = (const float*)d_in[0];   // [N, D]
    const float* C = (const float*)d_in[1];   // [K, D]
    int* out = (int*)d_out;

    char* ws = (char*)d_ws;
    const size_t c2_off  = 0;
    const size_t xhi_off = 8192;                                   // c2 = 8 KB
    const size_t xlo_off = xhi_off + (size_t)N_PTS * D_DIM * 2;    // +128 MB
    const size_t need = xlo_off + (size_t)N_PTS * D_DIM * 2;       // 268,443,648

    float*    c2  = (float*)(ws + c2_off);
    _Float16* Xhi = (_Float16*)(ws + xhi_off);
    _Float16* Xlo = (_Float16*)(ws + xlo_off);

    if (ws_size >= need) {
        row_norms_kernel<<<(K_CL * 64) / 256, 256, 0, stream>>>(C, c2, K_CL);
        conv_f16x2_kernel<<<(N_PTS * 64) / 256, 256, 0, stream>>>(X, Xhi, Xlo, N_PTS);
        kmeans_screen<<<N_PTS / BM, 256, 0, stream>>>(X, C, Xhi, c2, out);
        kmeans_rescue<<<N_PTS / 512, 256, 0, stream>>>(X, C, Xhi, Xlo, c2, out);
    }
    // (harness ws proven >= 272,637,952 in round 2; need < that, so no fallback path)
}